// Round 9
// baseline (624.222 us; speedup 1.0000x reference)
//
#include <hip/hip_runtime.h>
#include <hip/hip_bf16.h>
#include <math.h>

#define S_LEN   4096
#define B_SZ    32
#define D_DIM   64
#define L_LNK   13
#define NW_R    13
#define HF_W    128
#define HV_W    128
#define VOCAB_N 512
#define NC_N    2

#define STRIDE  512            // chord rows per thread-stride
#define NROW    8              // rows per thread
#define MIRROR  256            // mirrored rows (max LDS link offset)
#define BUFN    (S_LEN + MIRROR)
#define ZSCALE  (1.0f / 256.0f)   // fp16 range headroom (exact pow2)

typedef float vf4 __attribute__((ext_vector_type(4)));
typedef _Float16 hf2 __attribute__((ext_vector_type(2)));  // native, SROA-safe

__device__ __forceinline__ float gelu_erf(float x) {
    return 0.5f * x * (1.0f + erff(x * 0.70710678118654752440f));
}

// acc += c * z, z = 4 packed fp16 in a uint2, value-based casts only.
// fmaf(f32, fpext(f16), f32) is the v_fma_mix_f32 selection pattern.
__device__ __forceinline__ void fmamix4(vf4& acc, float c, uint2 z) {
    hf2 lo = __builtin_bit_cast(hf2, z.x);
    hf2 hi = __builtin_bit_cast(hf2, z.y);
    acc.x = fmaf(c, (float)lo.x, acc.x);
    acc.y = fmaf(c, (float)lo.y, acc.y);
    acc.z = fmaf(c, (float)hi.x, acc.z);
    acc.w = fmaf(c, (float)hi.y, acc.w);
}

__device__ __forceinline__ uint2 pack4h(vf4 v) {
    hf2 lo = {(_Float16)v.x, (_Float16)v.y};   // RNE
    hf2 hi = {(_Float16)v.z, (_Float16)v.w};
    uint2 r;
    r.x = __builtin_bit_cast(unsigned int, lo);
    r.y = __builtin_bit_cast(unsigned int, hi);
    return r;
}

__device__ __forceinline__ vf4 unpack4h(uint2 z) {
    hf2 lo = __builtin_bit_cast(hf2, z.x);
    hf2 hi = __builtin_bit_cast(hf2, z.y);
    vf4 r;
    r.x = (float)lo.x; r.y = (float)lo.y;
    r.z = (float)hi.x; r.w = (float)hi.y;
    return r;
}

__device__ __forceinline__ void cvt2(unsigned int w, float& a, float& b) {
    hf2 h = __builtin_bit_cast(hf2, w);
    a = (float)h.x; b = (float)h.y;
}

// ---------------------------------------------------------------------------
// Kernel A: per-token tables (parallel stage-2 split). F_table fp16,
// rows padded to 16 halves (32 B). Grid: 13*512 F + 512 V blocks x 128 thr.
// ---------------------------------------------------------------------------
__global__ __launch_bounds__(128)
void tables_kernel(const float* __restrict__ emb,
                   const float* __restrict__ fW1, const float* __restrict__ fb1,
                   const float* __restrict__ fW2, const float* __restrict__ fb2,
                   const float* __restrict__ vW1, const float* __restrict__ vb1,
                   const float* __restrict__ vW2, const float* __restrict__ vb2,
                   _Float16* __restrict__ F_table, float* __restrict__ V_table) {
    __shared__ float s_emb[D_DIM];
    __shared__ float s_H[HF_W];
    __shared__ float s_p[16][8];
    const int blk = blockIdx.x;
    const int tid = threadIdx.x;

    if (blk < NW_R * VOCAB_N) {
        const int k = blk >> 9;
        const int t = blk & (VOCAB_N - 1);
        if (tid < D_DIM) s_emb[tid] = emb[t * D_DIM + tid];
        __syncthreads();
        float acc = fb1[k * HF_W + tid];
        const float* w = fW1 + (size_t)k * D_DIM * HF_W + tid;
        #pragma unroll 8
        for (int d = 0; d < D_DIM; ++d) acc += s_emb[d] * w[d * HF_W];
        s_H[tid] = gelu_erf(acc);
        __syncthreads();
        // stage 2: output l = tid>>3 (13 used of 16), h-chunk = tid&7
        const int l = tid >> 3;
        const int part = tid & 7;
        if (l < L_LNK) {
            float p = 0.0f;
            const float* w2 = fW2 + (size_t)k * HF_W * L_LNK + l;
            #pragma unroll
            for (int h = part * 16; h < part * 16 + 16; ++h)
                p += s_H[h] * w2[h * L_LNK];
            s_p[l][part] = p;
        }
        __syncthreads();
        if (tid < 16) {
            float o = 0.0f;
            if (tid < L_LNK) {
                o = fb2[k * L_LNK + tid];
                #pragma unroll
                for (int i = 0; i < 8; ++i) o += s_p[tid][i];
            }
            F_table[((size_t)(k * VOCAB_N + t)) * 16 + tid] = (_Float16)o;
        }
    } else {
        const int t = blk - NW_R * VOCAB_N;
        if (tid < D_DIM) s_emb[tid] = emb[t * D_DIM + tid];
        __syncthreads();
        float acc = vb1[tid];
        const float* w = vW1 + tid;
        #pragma unroll 8
        for (int d = 0; d < D_DIM; ++d) acc += s_emb[d] * w[d * HV_W];
        s_H[tid] = gelu_erf(acc);
        __syncthreads();
        // stage 2: output d = tid&63, h-half = tid>>6
        const int d = tid & 63;
        const int part = tid >> 6;
        float p = 0.0f;
        const float* w2 = vW2 + d;
        #pragma unroll
        for (int h = part * 64; h < part * 64 + 64; ++h)
            p += s_H[h] * w2[h * D_DIM];
        s_p[d & 15][(d >> 4) * 2 + part] = p;   // 64x2 packed into 16x8
        __syncthreads();
        if (tid < D_DIM)
            V_table[t * D_DIM + tid] =
                vb2[tid] + s_p[tid & 15][(tid >> 4) * 2 + 0]
                         + s_p[tid & 15][(tid >> 4) * 2 + 1];
    }
}

// ---------------------------------------------------------------------------
// Kernel B (fused): blocks [0,64) = logits; blocks [64,576) = chord.
//
// amdgpu_waves_per_eu(4,4): LDS (69,632 B) already caps residency at
// 2 blocks/CU = 4 waves/EU, but the allocator's occupancy heuristic targets
// 8 waves/EU (64-VGPR budget) regardless — that mismatch caused the R3/R6/
// R7/R8 scratch-spill cliffs (~1.85 GB HBM traffic). Pinning waves/EU to 4
// raises the budget to 128 VGPRs at zero occupancy cost.
// ---------------------------------------------------------------------------
__global__ __launch_bounds__(512)
__attribute__((amdgpu_waves_per_eu(4, 4)))
void fused_kernel(const int* __restrict__ tok,
                  const _Float16* __restrict__ F_table,
                  const float* __restrict__ V_table,
                  const float* __restrict__ finW,
                  const float* __restrict__ finb,
                  float* __restrict__ out,
                  float* __restrict__ Zout) {
    __shared__ uint2 Zs[2][BUFN];
    const int blk = blockIdx.x;
    const int t = threadIdx.x;

    if (blk < B_SZ * NC_N) {
        // ---------------- logits branch ----------------
        const int b = blk >> 1;
        const int c = blk & 1;
        const float4* fin4 = (const float4*)(finW + (size_t)c * S_LEN * D_DIM);
        const float4* V4 = (const float4*)V_table;
        float acc = 0.0f;
        #pragma unroll
        for (int it = 0; it < 8; ++it) {
            const int s = t + it * 512;
            const int tk = tok[b * S_LEN + s];
            const float4* vp = V4 + tk * 16;
            const float4* fp = fin4 + s * 16;
            #pragma unroll
            for (int j = 0; j < 16; ++j) {
                float4 v = vp[j], f = fp[j];
                acc += v.x * f.x + v.y * f.y + v.z * f.z + v.w * f.w;
            }
        }
        #pragma unroll
        for (int o = 32; o > 0; o >>= 1) acc += __shfl_down(acc, o, 64);
        float* sp = (float*)&Zs[0][0];
        if ((t & 63) == 0) sp[t >> 6] = acc;
        __syncthreads();
        if (t == 0) {
            float s = finb[c];
            #pragma unroll
            for (int i = 0; i < 8; ++i) s += sp[i];
            out[b * NC_N + c] = s;
        }
        return;
    }

    // ---------------- chord branch ----------------
    const int cid = blk - B_SZ * NC_N;
    const int ds = cid & 15;        // dim slice
    const int b = cid >> 4;         // batch
    const vf4* V4 = (const vf4*)V_table;

    unsigned tokf[NROW];
    uint2 Vp[NROW], zp[NROW];
    #pragma unroll
    for (int j = 0; j < NROW; ++j) {
        const int r = t + STRIDE * j;
        const int tk = tok[b * S_LEN + r];
        tokf[j] = (unsigned)tk * 32u;
        vf4 v = V4[tk * 16 + ds] * ZSCALE;
        uint2 p = pack4h(v);
        Vp[j] = p; zp[j] = p;
        Zs[0][r] = p;
    }
    if (t < MIRROR) Zs[0][S_LEN + t] = zp[0];
    __syncthreads();

    int cur = 0;
    vf4 acc[NROW];
    #pragma unroll 1
    for (int k = 0; k < NW_R; ++k) {
        const char* Fk = (const char*)F_table + (size_t)k * (VOCAB_N * 32);
        const uint2* Zc = Zs[cur];
        #pragma unroll
        for (int j = 0; j < NROW; ++j) {
            const int r = t + STRIDE * j;
            const char* Fr = Fk + tokf[j];
            uint4 u0 = *(const uint4*)Fr;                 // coeffs 0..7
            uint2 u1 = *(const uint2*)(Fr + 16);          // coeffs 8..11
            unsigned u2 = *(const unsigned*)(Fr + 24);    // coeff 12 (+pad)
            // coeff -> offset: c0:0 c1:1 c2:2 c3:4 c4:8 c5:16 c6:32 c7:64
            //                  c8:128 c9:256 c10:512 c11:1024 c12:2048
            float c0,c1,c2,c3,c4,c5,c6,c7,c8,c9,c10,c11,c12,cp;
            cvt2(u0.x,c0,c1);  cvt2(u0.y,c2,c3);
            cvt2(u0.z,c4,c5);  cvt2(u0.w,c6,c7);
            cvt2(u1.x,c8,c9);  cvt2(u1.y,c10,c11);
            cvt2(u2,c12,cp);   (void)cp;

            vf4 a = unpack4h(Vp[j]);                   // residual
            fmamix4(a, c0,  zp[j]);                    // off 0
            fmamix4(a, c10, zp[(j + 1) & 7]);          // off 512
            fmamix4(a, c11, zp[(j + 2) & 7]);          // off 1024
            fmamix4(a, c12, zp[(j + 4) & 7]);          // off 2048
            fmamix4(a, c1, Zc[r + 1]);
            fmamix4(a, c2, Zc[r + 2]);
            fmamix4(a, c3, Zc[r + 4]);
            fmamix4(a, c4, Zc[r + 8]);
            fmamix4(a, c5, Zc[r + 16]);
            fmamix4(a, c6, Zc[r + 32]);
            fmamix4(a, c7, Zc[r + 64]);
            fmamix4(a, c8, Zc[r + 128]);
            fmamix4(a, c9, Zc[r + 256]);
            acc[j] = a;
        }
        if (k < NW_R - 1) {
            uint2* Zn = Zs[cur ^ 1];
            #pragma unroll
            for (int j = 0; j < NROW; ++j) {
                uint2 p = pack4h(acc[j]);
                zp[j] = p;
                Zn[t + STRIDE * j] = p;
            }
            if (t < MIRROR) Zn[S_LEN + t] = zp[0];
        }
        __syncthreads();   // single barrier/round (double buffer -> no WAR)
        cur ^= 1;
    }

    #pragma unroll
    for (int j = 0; j < NROW; ++j) {
        const int r = t + STRIDE * j;
        vf4 o = acc[j] * 256.0f;       // undo ZSCALE
        *(vf4*)(Zout + (((size_t)b * S_LEN + r) << 6) + ds * 4) = o;
    }
}

extern "C" void kernel_launch(void* const* d_in, const int* in_sizes, int n_in,
                              void* d_out, int out_size, void* d_ws, size_t ws_size,
                              hipStream_t stream) {
    const int*   tok  = (const int*)d_in[0];
    const float* emb  = (const float*)d_in[1];
    const float* fW1  = (const float*)d_in[2];
    const float* fb1  = (const float*)d_in[3];
    const float* fW2  = (const float*)d_in[4];
    const float* fb2  = (const float*)d_in[5];
    const float* vW1  = (const float*)d_in[6];
    const float* vb1  = (const float*)d_in[7];
    const float* vW2  = (const float*)d_in[8];
    const float* vb2  = (const float*)d_in[9];
    const float* finW = (const float*)d_in[10];
    const float* finb = (const float*)d_in[11];

    float* out = (float*)d_out;          // (B, NC) = 64 floats
    float* Z   = out + B_SZ * NC_N;      // (B, S, D) fp32

    float*    V_table = (float*)d_ws;                           // 512*64 f32
    _Float16* F_table = (_Float16*)(V_table + VOCAB_N * D_DIM); // 13*512*16 f16

    tables_kernel<<<NW_R * VOCAB_N + VOCAB_N, 128, 0, stream>>>(
        emb, fW1, fb1, fW2, fb2, vW1, vb1, vW2, vb2, F_table, V_table);
    fused_kernel<<<B_SZ * NC_N + 16 * B_SZ, 512, 0, stream>>>(
        tok, F_table, V_table, finW, finb, out, Z);
}

// Round 10
// 275.084 us; speedup vs baseline: 2.2692x; 2.2692x over previous
//
#include <hip/hip_runtime.h>
#include <hip/hip_bf16.h>
#include <hip/hip_fp16.h>
#include <math.h>

#define S_LEN   4096
#define B_SZ    32
#define D_DIM   64
#define L_LNK   13
#define NW_R    13
#define HF_W    128
#define HV_W    128
#define VOCAB_N 512
#define NC_N    2

#define STRIDE  512            // chord rows per thread-stride
#define NROW    8              // rows per thread
#define MIRROR  256            // mirrored rows (max LDS link offset)
#define BUFN    (S_LEN + MIRROR)

typedef float vf4 __attribute__((ext_vector_type(4)));

__device__ __forceinline__ float gelu_erf(float x) {
    return 0.5f * x * (1.0f + erff(x * 0.70710678118654752440f));
}

__device__ __forceinline__ void fma4(vf4& a, float s, vf4 z) {
    vf4 sv = {s, s, s, s};
    a = __builtin_elementwise_fma(z, sv, a);
}

// bf16x4 pack/unpack (order: lo16(x), hi16(x), lo16(y), hi16(y)) — R5 verbatim.
// NOTE: Z must stay bf16. Every fp16-Z variant (R6/R7/R8/R9, three different
// source expressions + waves_per_eu pin) hit a ~1.85 GB scratch-spill cliff
// at VGPR_Count=64; bf16 builds (R4/R5) are clean. Do not re-attempt fp16 Z.
__device__ __forceinline__ uint2 pack4(vf4 v) {
    __hip_bfloat162 a = __float22bfloat162_rn(float2{v.x, v.y});
    __hip_bfloat162 b = __float22bfloat162_rn(float2{v.z, v.w});
    uint2 r;
    r.x = *reinterpret_cast<unsigned int*>(&a);
    r.y = *reinterpret_cast<unsigned int*>(&b);
    return r;
}

__device__ __forceinline__ vf4 unpack4(uint2 u) {
    vf4 r;
    r.x = __uint_as_float(u.x << 16);
    r.y = __uint_as_float(u.x & 0xffff0000u);
    r.z = __uint_as_float(u.y << 16);
    r.w = __uint_as_float(u.y & 0xffff0000u);
    return r;
}

__device__ __forceinline__ void cvt2(unsigned int w, float& a, float& b) {
    __half2 h = *reinterpret_cast<__half2*>(&w);
    a = __half2float(h.x); b = __half2float(h.y);
}

// ---------------------------------------------------------------------------
// Kernel A: per-token tables, parallel stage-2 split (R8 version, proven).
// F_table fp16, rows padded to 16 halves (32 B). Grid: 13*512 + 512 x 128.
// ---------------------------------------------------------------------------
__global__ __launch_bounds__(128)
void tables_kernel(const float* __restrict__ emb,
                   const float* __restrict__ fW1, const float* __restrict__ fb1,
                   const float* __restrict__ fW2, const float* __restrict__ fb2,
                   const float* __restrict__ vW1, const float* __restrict__ vb1,
                   const float* __restrict__ vW2, const float* __restrict__ vb2,
                   __half* __restrict__ F_table, float* __restrict__ V_table) {
    __shared__ float s_emb[D_DIM];
    __shared__ float s_H[HF_W];
    __shared__ float s_p[16][8];
    const int blk = blockIdx.x;
    const int tid = threadIdx.x;

    if (blk < NW_R * VOCAB_N) {
        const int k = blk >> 9;
        const int t = blk & (VOCAB_N - 1);
        if (tid < D_DIM) s_emb[tid] = emb[t * D_DIM + tid];
        __syncthreads();
        float acc = fb1[k * HF_W + tid];
        const float* w = fW1 + (size_t)k * D_DIM * HF_W + tid;
        #pragma unroll 8
        for (int d = 0; d < D_DIM; ++d) acc += s_emb[d] * w[d * HF_W];
        s_H[tid] = gelu_erf(acc);
        __syncthreads();
        // stage 2: output l = tid>>3 (13 used of 16), h-chunk = tid&7
        const int l = tid >> 3;
        const int part = tid & 7;
        if (l < L_LNK) {
            float p = 0.0f;
            const float* w2 = fW2 + (size_t)k * HF_W * L_LNK + l;
            #pragma unroll
            for (int h = part * 16; h < part * 16 + 16; ++h)
                p += s_H[h] * w2[h * L_LNK];
            s_p[l][part] = p;
        }
        __syncthreads();
        if (tid < 16) {
            float o = 0.0f;
            if (tid < L_LNK) {
                o = fb2[k * L_LNK + tid];
                #pragma unroll
                for (int i = 0; i < 8; ++i) o += s_p[tid][i];
            }
            F_table[((size_t)(k * VOCAB_N + t)) * 16 + tid] = __float2half_rn(o);
        }
    } else {
        const int t = blk - NW_R * VOCAB_N;
        if (tid < D_DIM) s_emb[tid] = emb[t * D_DIM + tid];
        __syncthreads();
        float acc = vb1[tid];
        const float* w = vW1 + tid;
        #pragma unroll 8
        for (int d = 0; d < D_DIM; ++d) acc += s_emb[d] * w[d * HV_W];
        s_H[tid] = gelu_erf(acc);
        __syncthreads();
        // stage 2: output d = tid&63, h-half = tid>>6
        const int d = tid & 63;
        const int part = tid >> 6;
        float p = 0.0f;
        const float* w2 = vW2 + d;
        #pragma unroll
        for (int h = part * 64; h < part * 64 + 64; ++h)
            p += s_H[h] * w2[h * D_DIM];
        s_p[d & 15][(d >> 4) * 2 + part] = p;   // 64x2 packed into 16x8
        __syncthreads();
        if (tid < D_DIM)
            V_table[t * D_DIM + tid] =
                vb2[tid] + s_p[tid & 15][(tid >> 4) * 2 + 0]
                         + s_p[tid & 15][(tid >> 4) * 2 + 1];
    }
}

// ---------------------------------------------------------------------------
// Kernel B: logits. 64 blocks x 1024 threads, direct store (no memset, no
// atomics). Unroll capped (outer 1, inner 4) to bound register pressure.
// ---------------------------------------------------------------------------
__global__ __launch_bounds__(1024)
void logits_kernel(const int* __restrict__ tok,
                   const float* __restrict__ V_table,
                   const float* __restrict__ finW,
                   const float* __restrict__ finb,
                   float* __restrict__ out) {
    const int b = blockIdx.x >> 1;
    const int c = blockIdx.x & 1;
    const int tid = threadIdx.x;
    const float4* fin4 = (const float4*)(finW + (size_t)c * S_LEN * D_DIM);
    const float4* V4 = (const float4*)V_table;
    float acc = 0.0f;
    #pragma unroll 1
    for (int it = 0; it < 4; ++it) {
        const int s = tid + it * 1024;
        const int tk = tok[b * S_LEN + s];
        const float4* vp = V4 + tk * 16;
        const float4* fp = fin4 + s * 16;
        #pragma unroll 4
        for (int j = 0; j < 16; ++j) {
            float4 v = vp[j], f = fp[j];
            acc += v.x * f.x + v.y * f.y + v.z * f.z + v.w * f.w;
        }
    }
    #pragma unroll
    for (int o = 32; o > 0; o >>= 1) acc += __shfl_down(acc, o, 64);
    __shared__ float sp[16];
    if ((tid & 63) == 0) sp[tid >> 6] = acc;
    __syncthreads();
    if (tid == 0) {
        float s = finb[c];
        #pragma unroll
        for (int i = 0; i < 16; ++i) s += sp[i];
        out[b * NC_N + c] = s;
    }
}

// ---------------------------------------------------------------------------
// Kernel C: chord sparse-multiply — R5 VERBATIM (proven: 121 us, FETCH
// 3.9 MB / WRITE 65 MB, no spill, 0 bank conflicts).
// 512 threads, thread t owns rows t+512j (j=0..7):
//  - offsets 0/512/1024/2048 from packed-bf16 register array zp[8].
//  - 9 LDS links (1..256) from mirrored double-buffered bf16 Zs ->
//    ds_read_b64 with immediate offsets, ONE barrier per round.
//  - F fp16 rows via SGPR base + voffset.
// LDS 2*4352*8 = 69,632 B -> 2 blocks/CU -> 16 waves/CU.
// ---------------------------------------------------------------------------
__global__ __launch_bounds__(512, 4)
void chord_kernel(const int* __restrict__ tok,
                  const __half* __restrict__ F_table,
                  const float* __restrict__ V_table,
                  float* __restrict__ Zout) {
    __shared__ uint2 Zs[2][BUFN];
    const int b = blockIdx.y;
    const int ds = blockIdx.x;
    const int t = threadIdx.x;
    const vf4* V4 = (const vf4*)V_table;

    unsigned tokf[NROW];
    uint2 Vp[NROW], zp[NROW];
    #pragma unroll
    for (int j = 0; j < NROW; ++j) {
        const int r = t + STRIDE * j;
        const int tk = tok[b * S_LEN + r];
        tokf[j] = (unsigned)tk * 32u;
        vf4 v = V4[tk * 16 + ds];
        uint2 p = pack4(v);
        Vp[j] = p; zp[j] = p;
        Zs[0][r] = p;
    }
    if (t < MIRROR) Zs[0][S_LEN + t] = zp[0];
    __syncthreads();

    int cur = 0;
    vf4 acc[NROW];
    #pragma unroll 1
    for (int k = 0; k < NW_R; ++k) {
        const char* Fk = (const char*)F_table + (size_t)k * (VOCAB_N * 32);
        const uint2* Zc = Zs[cur];
        #pragma unroll
        for (int j = 0; j < NROW; ++j) {
            const int r = t + STRIDE * j;
            const char* Fr = Fk + tokf[j];
            uint4 u0 = *(const uint4*)Fr;                 // coeffs 0..7
            uint2 u1 = *(const uint2*)(Fr + 16);          // coeffs 8..11
            unsigned u2 = *(const unsigned*)(Fr + 24);    // coeff 12 (+pad)
            // coeff -> offset: c0:0 c1:1 c2:2 c3:4 c4:8 c5:16 c6:32 c7:64
            //                  c8:128 c9:256 c10:512 c11:1024 c12:2048
            float c0,c1,c2,c3,c4,c5,c6,c7,c8,c9,c10,c11,c12,cp;
            cvt2(u0.x,c0,c1);  cvt2(u0.y,c2,c3);
            cvt2(u0.z,c4,c5);  cvt2(u0.w,c6,c7);
            cvt2(u1.x,c8,c9);  cvt2(u1.y,c10,c11);
            cvt2(u2,c12,cp);   (void)cp;

            vf4 a = unpack4(Vp[j]);                    // residual
            fma4(a, c0,  unpack4(zp[j]));              // off 0
            fma4(a, c10, unpack4(zp[(j + 1) & 7]));    // off 512
            fma4(a, c11, unpack4(zp[(j + 2) & 7]));    // off 1024
            fma4(a, c12, unpack4(zp[(j + 4) & 7]));    // off 2048
            fma4(a, c1, unpack4(Zc[r + 1]));
            fma4(a, c2, unpack4(Zc[r + 2]));
            fma4(a, c3, unpack4(Zc[r + 4]));
            fma4(a, c4, unpack4(Zc[r + 8]));
            fma4(a, c5, unpack4(Zc[r + 16]));
            fma4(a, c6, unpack4(Zc[r + 32]));
            fma4(a, c7, unpack4(Zc[r + 64]));
            fma4(a, c8, unpack4(Zc[r + 128]));
            fma4(a, c9, unpack4(Zc[r + 256]));
            acc[j] = a;
        }
        if (k < NW_R - 1) {
            uint2* Zn = Zs[cur ^ 1];
            #pragma unroll
            for (int j = 0; j < NROW; ++j) {
                uint2 p = pack4(acc[j]);
                zp[j] = p;
                Zn[t + STRIDE * j] = p;
            }
            if (t < MIRROR) Zn[S_LEN + t] = zp[0];
        }
        __syncthreads();   // single barrier/round (double buffer -> no WAR)
        cur ^= 1;
    }

    #pragma unroll
    for (int j = 0; j < NROW; ++j) {
        const int r = t + STRIDE * j;
        *(vf4*)(Zout + (((size_t)b * S_LEN + r) << 6) + ds * 4) = acc[j];
    }
}

extern "C" void kernel_launch(void* const* d_in, const int* in_sizes, int n_in,
                              void* d_out, int out_size, void* d_ws, size_t ws_size,
                              hipStream_t stream) {
    const int*   tok  = (const int*)d_in[0];
    const float* emb  = (const float*)d_in[1];
    const float* fW1  = (const float*)d_in[2];
    const float* fb1  = (const float*)d_in[3];
    const float* fW2  = (const float*)d_in[4];
    const float* fb2  = (const float*)d_in[5];
    const float* vW1  = (const float*)d_in[6];
    const float* vb1  = (const float*)d_in[7];
    const float* vW2  = (const float*)d_in[8];
    const float* vb2  = (const float*)d_in[9];
    const float* finW = (const float*)d_in[10];
    const float* finb = (const float*)d_in[11];

    float* out = (float*)d_out;          // (B, NC) = 64 floats
    float* Z   = out + B_SZ * NC_N;      // (B, S, D) fp32

    float*  V_table = (float*)d_ws;                         // 512*64 f32
    __half* F_table = (__half*)(V_table + VOCAB_N * D_DIM); // 13*512*16 f16

    tables_kernel<<<NW_R * VOCAB_N + VOCAB_N, 128, 0, stream>>>(
        emb, fW1, fb1, fW2, fb2, vW1, vb1, vW2, vb2, F_table, V_table);
    logits_kernel<<<B_SZ * NC_N, 1024, 0, stream>>>(tok, V_table, finW, finb, out);
    chord_kernel<<<dim3(16, B_SZ), 512, 0, stream>>>(tok, F_table, V_table, Z);
}